// Round 11
// baseline (539.919 us; speedup 1.0000x reference)
//
#include <hip/hip_runtime.h>

#define NN 100000
#define NE 1600000
#define H  128
#define SCAN_CHUNK 512
#define NB_SCAN ((NN + SCAN_CHUNK - 1) / SCAN_CHUNK)   // 196

// ---------------- zero int array ----------------
__global__ void zero_int(int* __restrict__ p, int n) {
    int i = blockIdx.x * blockDim.x + threadIdx.x;
    if (i < n) p[i] = 0;
}

// ---------------- histogram of dst ----------------
__global__ void hist_kernel(const int* __restrict__ ei, int* __restrict__ deg) {
    int e = blockIdx.x * 256 + threadIdx.x;
    if (e < NE) atomicAdd(&deg[ei[NE + e]], 1);
}

// ---------------- per-chunk exclusive scan ----------------
__global__ __launch_bounds__(SCAN_CHUNK) void scan_block(const int* __restrict__ deg,
                                                         int* __restrict__ off,
                                                         int* __restrict__ sums, int n) {
    __shared__ int buf[SCAN_CHUNK];
    int base = blockIdx.x * SCAN_CHUNK;
    int t = threadIdx.x;
    int v = (base + t < n) ? deg[base + t] : 0;
    buf[t] = v;
    __syncthreads();
    for (int s = 1; s < SCAN_CHUNK; s <<= 1) {
        int add = (t >= s) ? buf[t - s] : 0;
        __syncthreads();
        buf[t] += add;
        __syncthreads();
    }
    if (base + t < n) off[base + t] = buf[t] - v;
    if (t == SCAN_CHUNK - 1) sums[blockIdx.x] = buf[t];
}

__global__ __launch_bounds__(256) void scan_sums(int* __restrict__ sums, int nb) {
    __shared__ int buf[256];
    int t = threadIdx.x;
    int v = (t < nb) ? sums[t] : 0;
    buf[t] = v;
    __syncthreads();
    for (int s = 1; s < 256; s <<= 1) {
        int add = (t >= s) ? buf[t - s] : 0;
        __syncthreads();
        buf[t] += add;
        __syncthreads();
    }
    if (t < nb) sums[t] = buf[t] - v;
}

__global__ void scan_add(int* __restrict__ off, const int* __restrict__ sums,
                         int* __restrict__ cur, int n) {
    int i = blockIdx.x * 256 + threadIdx.x;
    if (i < n) {
        int v = off[i] + sums[i >> 9];
        off[i] = v;
        cur[i] = v;
    }
}

// ---------------- fill CSR with packed (src, weight) ----------------
__global__ void fill_kernel(const int* __restrict__ ei, const float* __restrict__ ew,
                            int* __restrict__ cur, int2* __restrict__ csr) {
    int e = blockIdx.x * 256 + threadIdx.x;
    if (e >= NE) return;
    int d = ei[NE + e];
    int pos = atomicAdd(&cur[d], 1);
    csr[pos] = make_int2(ei[e], __float_as_int(ew[e]));
}

// ---------------- convert W_edge f32 -> packed bf16 (RNE) ----------------
__global__ void conv_bf16(const float* __restrict__ in, unsigned int* __restrict__ outp,
                          int n2) {
    int i = blockIdx.x * 256 + threadIdx.x;
    if (i >= n2) return;
    float2 v = *reinterpret_cast<const float2*>(&in[(long long)i * 2]);
    unsigned int b0 = __float_as_uint(v.x);
    unsigned int b1 = __float_as_uint(v.y);
    b0 = (b0 + 0x7fffu + ((b0 >> 16) & 1u)) >> 16;
    b1 = (b1 + 0x7fffu + ((b1 >> 16) & 1u)) >> 16;
    outp[i] = b0 | (b1 << 16);
}

// ---- merged precompute: blocks 0..127 -> W3 rows; block 128 -> b4 ----
__global__ __launch_bounds__(128) void precompute_all(const float* __restrict__ W_node,
                                                      const float* __restrict__ W_cat2,
                                                      const float* __restrict__ b_edge,
                                                      const float* __restrict__ W_cat1,
                                                      const float* __restrict__ b_node,
                                                      const float* __restrict__ b_cat1,
                                                      const float* __restrict__ b_cat2,
                                                      float* __restrict__ W3,
                                                      float* __restrict__ b4) {
    int c = threadIdx.x;
    if (blockIdx.x < H) {
        int k = blockIdx.x;
        __shared__ float wrow[H];
        wrow[c] = W_node[k * H + c];
        __syncthreads();
        float acc = wrow[c];   // identity part of (I + W_cat2)
        #pragma unroll 8
        for (int j = 0; j < H; ++j)
            acc += wrow[j] * W_cat2[j * H + c];
        W3[k * H + c] = acc;
    } else {
        __shared__ float be[H], bn[H];
        be[c] = b_edge[c];
        bn[c] = b_node[c];
        __syncthreads();
        float acc = be[c] + bn[c] + b_cat1[c] + b_cat2[c];
        for (int j = 0; j < H; ++j)
            acc += be[j] * W_cat1[j * H + c] + bn[j] * W_cat2[j * H + c];
        b4[c] = acc;
    }
}

// ------- fully fused, TR=32 rows/block, 512 threads (8 waves) -------
// Gather: wave w -> rows 4w..4w+3 (all 128 ch via 64 lanes x bf16-pair).
// Phases B/C: wave w -> 16-COLUMN slice [16w,16w+16) for ALL 32 rows:
// per-wave weight traffic drops 64KB -> 8KB per matrix (8x less L2 traffic).
__global__ __launch_bounds__(512, 2) void gather_fused(const int* __restrict__ off,
                                                       const int* __restrict__ end,
                                                       const int2* __restrict__ csr,
                                                       const unsigned int* __restrict__ wbf,
                                                       const float* __restrict__ x,
                                                       const float* __restrict__ Wc1,
                                                       const float* __restrict__ W3,
                                                       const float* __restrict__ b4,
                                                       const float* __restrict__ Wf,
                                                       const float* __restrict__ bf,
                                                       float* __restrict__ out,
                                                       int nrows) {
    const int TR = 32;
    __shared__ float As[TR][H];
    __shared__ float Xs[TR][H];
    int row0 = blockIdx.x * TR;
    int tid = threadIdx.x;

    // load Xs (x rows): 32*128 floats = 1024 float4 over 512 threads
    for (int i = tid; i < TR * H / 4; i += 512) {
        int fi = i * 4;
        int rr = fi >> 7, cc = fi & 127;
        float4 xv = {0.f, 0.f, 0.f, 0.f};
        if (row0 + rr < nrows)
            xv = *reinterpret_cast<const float4*>(&x[(long long)(row0 + rr) * H + cc]);
        *reinterpret_cast<float4*>(&Xs[rr][cc]) = xv;
    }

    // ---- phase A: gather (bf16 rows). wave w handles rows 4w..4w+3 ----
    int wv = tid >> 6;        // 0..7
    int lane = tid & 63;
    #pragma unroll
    for (int rr4 = 0; rr4 < 4; ++rr4) {
        int rr = wv * 4 + rr4;
        int d = row0 + rr;
        float ax = 0.f, ay = 0.f;
        if (d < nrows) {
            int i0 = __builtin_amdgcn_readfirstlane(off[d]);
            int i1 = __builtin_amdgcn_readfirstlane(end[d]);
            int j = i0;
            for (; j + 4 <= i1; j += 4) {
                int2 e0 = csr[j];
                int2 e1 = csr[j + 1];
                int2 e2 = csr[j + 2];
                int2 e3 = csr[j + 3];
                unsigned int u0 = wbf[(long long)e0.x * 64 + lane];
                unsigned int u1 = wbf[(long long)e1.x * 64 + lane];
                unsigned int u2 = wbf[(long long)e2.x * 64 + lane];
                unsigned int u3 = wbf[(long long)e3.x * 64 + lane];
                float w0 = __int_as_float(e0.y), w1 = __int_as_float(e1.y);
                float w2 = __int_as_float(e2.y), w3 = __int_as_float(e3.y);
                ax += w0 * __uint_as_float(u0 << 16) + w1 * __uint_as_float(u1 << 16)
                    + w2 * __uint_as_float(u2 << 16) + w3 * __uint_as_float(u3 << 16);
                ay += w0 * __uint_as_float(u0 & 0xffff0000u) + w1 * __uint_as_float(u1 & 0xffff0000u)
                    + w2 * __uint_as_float(u2 & 0xffff0000u) + w3 * __uint_as_float(u3 & 0xffff0000u);
            }
            for (; j < i1; ++j) {
                int2 e = csr[j];
                float w = __int_as_float(e.y);
                unsigned int u = wbf[(long long)e.x * 64 + lane];
                ax += w * __uint_as_float(u << 16);
                ay += w * __uint_as_float(u & 0xffff0000u);
            }
        }
        *reinterpret_cast<float2*>(&As[rr][lane * 2]) = make_float2(ax, ay);
    }
    __syncthreads();

    // ---- phase B: t4 = agg + agg@Wc1 + x@W3 + b4 (column-tiled waves) ----
    // wave wv: cols [16*wv, 16*wv+16); lane: col-pair (lane&7), rows (lane>>3)*4..+3
    int c2 = wv * 16 + (lane & 7) * 2;
    int rbase = (lane >> 3) * 4;           // 0,4,...,28
    float2 b4v = *reinterpret_cast<const float2*>(&b4[c2]);
    float acc[4][2];
    #pragma unroll
    for (int r = 0; r < 4; ++r) {
        acc[r][0] = As[rbase + r][c2]     + b4v.x;   // identity term of (I + W_cat1)
        acc[r][1] = As[rbase + r][c2 + 1] + b4v.y;
    }

    for (int k = 0; k < H; k += 4) {
        float2 w1[4], w3[4];
        #pragma unroll
        for (int kk = 0; kk < 4; ++kk) {
            w1[kk] = *reinterpret_cast<const float2*>(&Wc1[(k + kk) * H + c2]);
            w3[kk] = *reinterpret_cast<const float2*>(&W3[(k + kk) * H + c2]);
        }
        #pragma unroll
        for (int r = 0; r < 4; ++r) {
            float4 a  = *reinterpret_cast<const float4*>(&As[rbase + r][k]);
            float4 xv = *reinterpret_cast<const float4*>(&Xs[rbase + r][k]);
            acc[r][0] += a.x * w1[0].x + a.y * w1[1].x + a.z * w1[2].x + a.w * w1[3].x
                       + xv.x * w3[0].x + xv.y * w3[1].x + xv.z * w3[2].x + xv.w * w3[3].x;
            acc[r][1] += a.x * w1[0].y + a.y * w1[1].y + a.z * w1[2].y + a.w * w1[3].y
                       + xv.x * w3[0].y + xv.y * w3[1].y + xv.z * w3[2].y + xv.w * w3[3].y;
        }
    }

    // ---- relu, stash back to LDS ----
    __syncthreads();   // all phase-B reads of As complete
    #pragma unroll
    for (int r = 0; r < 4; ++r) {
        As[rbase + r][c2]     = fmaxf(acc[r][0], 0.f);
        As[rbase + r][c2 + 1] = fmaxf(acc[r][1], 0.f);
    }
    __syncthreads();

    // ---- phase C: out = relu(t4) @ Wf + bf (same column tiling) ----
    float2 bfv = *reinterpret_cast<const float2*>(&bf[c2]);
    float acc2[4][2];
    #pragma unroll
    for (int r = 0; r < 4; ++r) {
        acc2[r][0] = bfv.x;
        acc2[r][1] = bfv.y;
    }

    for (int k = 0; k < H; k += 4) {
        float2 wf[4];
        #pragma unroll
        for (int kk = 0; kk < 4; ++kk)
            wf[kk] = *reinterpret_cast<const float2*>(&Wf[(k + kk) * H + c2]);
        #pragma unroll
        for (int r = 0; r < 4; ++r) {
            float4 v = *reinterpret_cast<const float4*>(&As[rbase + r][k]);
            acc2[r][0] += v.x * wf[0].x + v.y * wf[1].x + v.z * wf[2].x + v.w * wf[3].x;
            acc2[r][1] += v.x * wf[0].y + v.y * wf[1].y + v.z * wf[2].y + v.w * wf[3].y;
        }
    }

    #pragma unroll
    for (int r = 0; r < 4; ++r) {
        int row = row0 + rbase + r;
        if (row < nrows) {
            float2 o{acc2[r][0], acc2[r][1]};
            *reinterpret_cast<float2*>(&out[(long long)row * H + c2]) = o;
        }
    }
}

extern "C" void kernel_launch(void* const* d_in, const int* in_sizes, int n_in,
                              void* d_out, int out_size, void* d_ws, size_t ws_size,
                              hipStream_t stream) {
    const float* x       = (const float*)d_in[0];
    const int*   ei      = (const int*)d_in[1];
    const float* ew      = (const float*)d_in[2];
    const float* W_edge  = (const float*)d_in[3];
    const float* b_edge  = (const float*)d_in[4];
    const float* W_node  = (const float*)d_in[5];
    const float* b_node  = (const float*)d_in[6];
    const float* W_cat1  = (const float*)d_in[7];
    const float* b_cat1  = (const float*)d_in[8];
    const float* W_cat2  = (const float*)d_in[9];
    const float* b_cat2  = (const float*)d_in[10];
    const float* W_final = (const float*)d_in[11];
    const float* b_final = (const float*)d_in[12];
    float* out = (float*)d_out;

    // workspace layout
    int*  deg  = (int*)d_ws;                         // NN
    int*  off  = deg + NN;                           // NN
    int*  cur  = off + NN;                           // NN
    int*  sums = cur + NN;                           // 512
    int2* csr  = (int2*)(sums + 512);                // NE   (8B aligned: offset 1202048)
    unsigned int* wbf = (unsigned int*)(csr + NE);   // NN*64 packed bf16 pairs (25.6 MB)
    float* W3  = (float*)(wbf + (size_t)NN * 64);    // H*H
    float* b4  = W3 + H * H;                         // H

    // 1. CSR build
    zero_int<<<(NN + 255) / 256, 256, 0, stream>>>(deg, NN);
    hist_kernel<<<(NE + 255) / 256, 256, 0, stream>>>(ei, deg);
    scan_block<<<NB_SCAN, SCAN_CHUNK, 0, stream>>>(deg, off, sums, NN);
    scan_sums<<<1, 256, 0, stream>>>(sums, NB_SCAN);
    scan_add<<<(NN + 255) / 256, 256, 0, stream>>>(off, sums, cur, NN);
    fill_kernel<<<(NE + 255) / 256, 256, 0, stream>>>(ei, ew, cur, csr);

    // 2. W_edge -> bf16, merged precompute (W3 + b4)
    conv_bf16<<<(NN * H / 2 + 255) / 256, 256, 0, stream>>>(W_edge, wbf, NN * H / 2);
    precompute_all<<<H + 1, H, 0, stream>>>(W_node, W_cat2, b_edge, W_cat1,
                                            b_node, b_cat1, b_cat2, W3, b4);

    // 3. fully fused gather + affine + relu + final linear -> d_out
    gather_fused<<<(NN + 31) / 32, 512, 0, stream>>>(off, cur, csr, wbf, x,
                                                     W_cat1, W3, b4,
                                                     W_final, b_final, out, NN);
}